// Round 3
// baseline (225.802 us; speedup 1.0000x reference)
//
#include <hip/hip_runtime.h>

// Bilateral slice: grid (N=4, C=12, GD=8, GH=16, GW=16) fp32,
// guide (N,1,1024,1024) fp32 -> out (N, C, 1024, 1024) fp32.
//
// One block per image row. Two LDS staging passes:
//   pass 1: y-lerp grid rows -> rs[c][z][gx]      (wave-uniform wy per row)
//   pass 2: gather 2x2 (x,z) corners per cell -> c4[c][gx][z] as float4
// Per pixel per channel the trilinear gather is then ONE ds_read_b128 + 4 FMA.
// Edge clamps folded into adjusted t (base clamped, t shifted into [0,1]).
// c4 gx-stride padded to 9 float4 (36 dwords = 4 mod 32) so random-z lanes
// spread across bank groups: bank = 4*((bx+bz) mod 8).

#define NN 4
#define CC 12
#define GD_ 8
#define GH_ 16
#define GW_ 16
#define HH 1024
#define WW 1024

#define ZSTR 17                  // rs z-stride (floats)
#define RS_CSTR (GD_ * ZSTR)     // 136
#define C4_GXSTR 9               // c4 gx-stride in float4 (8 used + 1 pad)
#define C4_CSTR (GW_ * C4_GXSTR) // 144 float4 per channel

typedef float f32x4 __attribute__((ext_vector_type(4)));  // native vec for nontemporal store

__global__ __launch_bounds__(256) void slice_kernel(
    const float* __restrict__ grid,   // (N, C, GD, GH, GW)
    const float* __restrict__ guide,  // (N, 1, H, W)
    float* __restrict__ out)          // (N, C, H, W)
{
    __shared__ float  rs[CC * RS_CSTR + 8];   // 6.6 KB
    __shared__ float4 c4[CC * C4_CSTR];       // 27.6 KB

    const int row = blockIdx.x;        // 0 .. N*H-1
    const int n   = row >> 10;
    const int y   = row & (HH - 1);
    const int tid = threadIdx.x;

    // Kick off the guide load early (independent of staging).
    const float4 g4 = ((const float4*)guide)[((size_t)n * HH + y) * (WW / 4) + tid];

    // ---- y weights (uniform across the row) ----
    float ys = ((float)y + 0.5f) * (1.0f / 64.0f);   // * GH / H
    float fy = floorf(ys - 0.5f);
    int   by = (int)fy;
    by = by < 0 ? 0 : (by > GH_ - 2 ? GH_ - 2 : by);
    float ty = (ys - 0.5f - fy) + (float)((int)fy - by);
    ty = ty < 0.0f ? 0.0f : (ty > 1.0f ? 1.0f : ty);
    const float wy0 = 1.0f - ty, wy1 = ty;

    // ---- pass 1: y-lerped grid rows into rs ----
    const float* gbase = grid + (size_t)n * (CC * GD_ * GH_ * GW_);
    for (int idx = tid; idx < CC * GD_ * GW_; idx += 256) {
        int gx = idx & 15;
        int z  = (idx >> 4) & 7;
        int c  = idx >> 7;
        const float* gp = gbase + ((c * GD_ + z) * GH_) * GW_ + gx;
        float g0 = gp[by * GW_];
        float g1 = gp[(by + 1) * GW_];
        rs[c * RS_CSTR + z * ZSTR + gx] = wy0 * g0 + wy1 * g1;
    }
    __syncthreads();

    // ---- pass 2: pack 2x2 (x,z) corners into float4 per cell ----
    for (int idx = tid; idx < CC * GW_ * GD_; idx += 256) {
        int z   = idx & 7;
        int gx  = (idx >> 3) & 15;
        int c   = idx >> 7;
        int z1  = z  < GD_ - 1 ? z  + 1 : z;
        int gx1 = gx < GW_ - 1 ? gx + 1 : gx;
        const float* rc = rs + c * RS_CSTR;
        float v00 = rc[z  * ZSTR + gx ];
        float v01 = rc[z  * ZSTR + gx1];
        float v10 = rc[z1 * ZSTR + gx ];
        float v11 = rc[z1 * ZSTR + gx1];
        c4[c * C4_CSTR + gx * C4_GXSTR + z] = make_float4(v00, v01, v10, v11);
    }
    __syncthreads();

    // ---- per-pixel setup: 4 consecutive pixels per thread ----
    float gz[4] = {g4.x, g4.y, g4.z, g4.w};

    int   off4[4];
    float w00[4], w01[4], w10[4], w11[4];
#pragma unroll
    for (int j = 0; j < 4; ++j) {
        int   x  = tid * 4 + j;
        float xs = ((float)x + 0.5f) * (1.0f / 64.0f);  // * GW / W
        float fx = floorf(xs - 0.5f);
        int   bx = (int)fx;
        bx = bx < 0 ? 0 : (bx > GW_ - 2 ? GW_ - 2 : bx);
        float tx = (xs - 0.5f - fx) + (float)((int)fx - bx);
        tx = tx < 0.0f ? 0.0f : (tx > 1.0f ? 1.0f : tx);

        float zs = gz[j] * 8.0f;                        // * GD
        float fz = floorf(zs - 0.5f);
        int   bz = (int)fz;
        bz = bz < 0 ? 0 : (bz > GD_ - 2 ? GD_ - 2 : bz);
        float tz = (zs - 0.5f - fz) + (float)((int)fz - bz);
        tz = tz < 0.0f ? 0.0f : (tz > 1.0f ? 1.0f : tz);

        off4[j] = bx * C4_GXSTR + bz;                   // float4 index (c offset folds to imm)
        float tx0 = 1.0f - tx, tz0 = 1.0f - tz;
        w00[j] = tz0 * tx0;  w01[j] = tz0 * tx;
        w10[j] = tz  * tx0;  w11[j] = tz  * tx;
    }

    // ---- channel loop: one ds_read_b128 + 4 FMA per (c, pixel) ----
    f32x4* out4 = (f32x4*)out;
#pragma unroll
    for (int c = 0; c < CC; ++c) {
        float acc[4];
#pragma unroll
        for (int j = 0; j < 4; ++j) {
            float4 v = c4[c * C4_CSTR + off4[j]];
            acc[j] = w00[j] * v.x + w01[j] * v.y + w10[j] * v.z + w11[j] * v.w;
        }
        f32x4 o = {acc[0], acc[1], acc[2], acc[3]};
        __builtin_nontemporal_store(
            o, &out4[(((size_t)n * CC + c) * HH + y) * (WW / 4) + tid]);
    }
}

extern "C" void kernel_launch(void* const* d_in, const int* in_sizes, int n_in,
                              void* d_out, int out_size, void* d_ws, size_t ws_size,
                              hipStream_t stream) {
    const float* grid  = (const float*)d_in[0];
    const float* guide = (const float*)d_in[1];
    float* out = (float*)d_out;
    dim3 gridDim(NN * HH);
    dim3 blockDim(256);
    hipLaunchKernelGGL(slice_kernel, gridDim, blockDim, 0, stream, grid, guide, out);
}

// Round 4
// 221.994 us; speedup vs baseline: 1.0172x; 1.0172x over previous
//
#include <hip/hip_runtime.h>

// Bilateral slice: grid (N=4, C=12, GD=8, GH=16, GW=16) fp32,
// guide (N,1,1024,1024) fp32 -> out (N, C, 1024, 1024) fp32.
//
// One block per image row. y-lerp of the grid is wave-uniform per row ->
// precompute r[c][z][gx] in LDS once per block (1536 floats, 6.6 KB ->
// high occupancy), then each pixel does a 4-tap (x,z) bilinear per channel
// (pairs of adjacent-offset reads -> ds_read2_b32). Edge clamps folded into
// adjusted t. Output: nontemporal float4 stores (write stream bypasses L2).
//
// Roofline: 192 MiB out + 16 MiB guide @ ~6.4 TB/s ≈ 33 µs; LDS gather
// (192 B/pixel, the minimum) ≈ 15 µs/CU and VALU ≈ 10 µs both overlap.

#define NN 4
#define CC 12
#define GD_ 8
#define GH_ 16
#define GW_ 16
#define HH 1024
#define WW 1024

#define ZSTR 17                  // z-stride 17: spreads random-z lanes across banks
#define CSTR (GD_ * ZSTR)        // 136 floats per channel

typedef float f32x4 __attribute__((ext_vector_type(4)));

__global__ __launch_bounds__(256) void slice_kernel(
    const float* __restrict__ grid,   // (N, C, GD, GH, GW)
    const float* __restrict__ guide,  // (N, 1, H, W)
    float* __restrict__ out)          // (N, C, H, W)
{
    __shared__ float r[CC * CSTR + 8];   // 6.6 KB

    const int row = blockIdx.x;        // 0 .. N*H-1
    const int n   = row >> 10;
    const int y   = row & (HH - 1);
    const int tid = threadIdx.x;

    // Kick off the guide load early (independent of staging).
    const float4 g4 = ((const float4*)guide)[((size_t)n * HH + y) * (WW / 4) + tid];

    // ---- y weights (wave-uniform across the row) ----
    float ys = ((float)y + 0.5f) * (1.0f / 64.0f);   // * GH / H
    float fy = floorf(ys - 0.5f);
    int   by = (int)fy;
    by = by < 0 ? 0 : (by > GH_ - 2 ? GH_ - 2 : by);
    float ty = (ys - 0.5f - fy) + (float)((int)fy - by);
    ty = ty < 0.0f ? 0.0f : (ty > 1.0f ? 1.0f : ty);
    const float wy0 = 1.0f - ty, wy1 = ty;

    // ---- stage y-lerped grid rows into LDS ----
    const float* gbase = grid + (size_t)n * (CC * GD_ * GH_ * GW_);
    for (int idx = tid; idx < CC * GD_ * GW_; idx += 256) {
        int gx = idx & 15;
        int z  = (idx >> 4) & 7;
        int c  = idx >> 7;
        const float* gp = gbase + ((c * GD_ + z) * GH_) * GW_ + gx;
        float g0 = gp[by * GW_];
        float g1 = gp[(by + 1) * GW_];
        r[c * CSTR + z * ZSTR + gx] = wy0 * g0 + wy1 * g1;
    }
    __syncthreads();

    // ---- per-pixel setup: 4 consecutive pixels per thread ----
    float gz[4] = {g4.x, g4.y, g4.z, g4.w};

    int   off0[4];
    float w00[4], w01[4], w10[4], w11[4];
#pragma unroll
    for (int j = 0; j < 4; ++j) {
        int   x  = tid * 4 + j;
        float xs = ((float)x + 0.5f) * (1.0f / 64.0f);  // * GW / W
        float fx = floorf(xs - 0.5f);
        int   bx = (int)fx;
        bx = bx < 0 ? 0 : (bx > GW_ - 2 ? GW_ - 2 : bx);
        float tx = (xs - 0.5f - fx) + (float)((int)fx - bx);
        tx = tx < 0.0f ? 0.0f : (tx > 1.0f ? 1.0f : tx);

        float zs = gz[j] * 8.0f;                        // * GD
        float fz = floorf(zs - 0.5f);
        int   bz = (int)fz;
        bz = bz < 0 ? 0 : (bz > GD_ - 2 ? GD_ - 2 : bz);
        float tz = (zs - 0.5f - fz) + (float)((int)fz - bz);
        tz = tz < 0.0f ? 0.0f : (tz > 1.0f ? 1.0f : tz);

        off0[j] = bz * ZSTR + bx;
        float tx0 = 1.0f - tx, tz0 = 1.0f - tz;
        w00[j] = tz0 * tx0;  w01[j] = tz0 * tx;
        w10[j] = tz  * tx0;  w11[j] = tz  * tx;
    }

    // ---- channel loop: 4-tap bilinear from LDS (ds_read2 pairs), nt store ----
    f32x4* out4 = (f32x4*)out;
#pragma unroll
    for (int c = 0; c < CC; ++c) {
        const float* rc = r + c * CSTR;
        float acc[4];
#pragma unroll
        for (int j = 0; j < 4; ++j) {
            const float* p0 = rc + off0[j];
            float a0 = p0[0],    a1 = p0[1];
            float b0 = p0[ZSTR], b1 = p0[ZSTR + 1];
            acc[j] = w00[j] * a0 + w01[j] * a1 + w10[j] * b0 + w11[j] * b1;
        }
        f32x4 o = {acc[0], acc[1], acc[2], acc[3]};
        __builtin_nontemporal_store(
            o, &out4[(((size_t)n * CC + c) * HH + y) * (WW / 4) + tid]);
    }
}

extern "C" void kernel_launch(void* const* d_in, const int* in_sizes, int n_in,
                              void* d_out, int out_size, void* d_ws, size_t ws_size,
                              hipStream_t stream) {
    const float* grid  = (const float*)d_in[0];
    const float* guide = (const float*)d_in[1];
    float* out = (float*)d_out;
    dim3 gridDim(NN * HH);
    dim3 blockDim(256);
    hipLaunchKernelGGL(slice_kernel, gridDim, blockDim, 0, stream, grid, guide, out);
}